// Round 8
// baseline (560.595 us; speedup 1.0000x reference)
//
#include <hip/hip_runtime.h>

typedef __attribute__((ext_vector_type(8))) short bf16x8;
typedef __attribute__((ext_vector_type(4))) float f32x4;

#define DEVFN __device__ __forceinline__

DEVFN short f2bf(float f) {
    union { float f; unsigned u; } v; v.f = f;
    unsigned r = (v.u + 0x7FFFu + ((v.u >> 16) & 1u)) >> 16;
    return (short)(unsigned short)r;
}
DEVFN float bf2f(short h) {
    union { unsigned u; float f; } v; v.u = ((unsigned)(unsigned short)h) << 16;
    return v.f;
}
DEVFN float2 bfpair(unsigned u) {
    union { unsigned v; float f; } a, b;
    a.v = u << 16; b.v = u & 0xFFFF0000u;
    float2 r; r.x = a.f; r.y = b.f; return r;
}
DEVFN unsigned packbf(float a, float b) {
    return (unsigned)(unsigned short)f2bf(a) | ((unsigned)(unsigned short)f2bf(b) << 16);
}

// Column permutation folded into weights: MFMA col c computes original col P(c),
// P(c) = (c&15)*8 + (c>>4). Lane (colbase) owns contiguous original cols
// colbase*8 .. colbase*8+7  ->  all epilogue stores are 16B/lane contiguous.
// B fragments are read DIRECTLY from global (32KB Bp fits L1; per-lane-contiguous
// 1KB segments) -- no LDS stage, no barrier, 36-deep vmem MLP per wave.

// ---------------- prep kernels ----------------

__global__ __launch_bounds__(128) void build_w1p_k(
    const float* __restrict__ Wb, const float* __restrict__ We1,
    const float* __restrict__ bb, const float* __restrict__ be1,
    float* __restrict__ W1p, float* __restrict__ b1p)
{
    int j = threadIdx.x;
    const float* B = We1 + 128 * 128;
    int i = blockIdx.x;
    if (i < 200) {
        float a = 0.f;
        for (int m = 0; m < 128; m++) a += Wb[i * 128 + m] * B[m * 128 + j];
        W1p[i * 128 + j] = a;
    } else {
        float a = be1[j];
        for (int m = 0; m < 128; m++) a += bb[m] * B[m * 128 + j];
        b1p[j] = a;
    }
}

__global__ __launch_bounds__(128) void build_tab_k(
    const float* __restrict__ W1p, const float* __restrict__ b1p,
    short* __restrict__ tab)
{
    int i = blockIdx.x;   // 0..1024
    int c = blockIdx.y;   // 0..3
    int j = threadIdx.x;
    float t = (float)i * (1.0f / 1024.0f);
    float acc = (c == 0) ? b1p[j] : 0.f;
    int kc = (int)(t * 49.f + 0.5f);
    for (int dk = -6; dk <= 6; dk++) {
        int k = kc + dk;
        if (k >= 0 && k < 50) {
            float d = t - (float)k * (1.f / 49.f);
            float g = expf(-1250.f * d * d);
            acc += g * W1p[(c * 50 + k) * 128 + j];
        }
    }
    tab[((size_t)(c * 1025 + i)) * 128 + j] = f2bf(acc);
}

// fragment build with column permutation P(col)
__global__ __launch_bounds__(256) void fold_plain_k(
    const float* __restrict__ W0, const float* __restrict__ W1,
    const float* __restrict__ W2, const float* __restrict__ W3,
    short* __restrict__ O0, short* __restrict__ O1,
    short* __restrict__ O2, short* __restrict__ O3)
{
    const float* W = (blockIdx.y == 0) ? W0 : (blockIdx.y == 1) ? W1 : (blockIdx.y == 2) ? W2 : W3;
    short* O = (blockIdx.y == 0) ? O0 : (blockIdx.y == 1) ? O1 : (blockIdx.y == 2) ? O2 : O3;
    int idx = blockIdx.x * 256 + threadIdx.x;
    int n = idx >> 8, ks = (idx >> 6) & 3, lane = idx & 63;
    int k8 = ks * 32 + (lane >> 4) * 8;
    int pcol = (lane & 15) * 8 + n;              // P(n*16 + colbase)
    bf16x8 fv;
    #pragma unroll
    for (int i2 = 0; i2 < 8; i2++) fv[i2] = f2bf(W[(k8 + i2) * 128 + pcol]);
    *(bf16x8*)(O + (size_t)idx * 8) = fv;
}

__global__ __launch_bounds__(256) void fold_k(
    const float* __restrict__ W, const float* __restrict__ bias,
    const float* __restrict__ statsG, const float* __restrict__ gamma,
    const float* __restrict__ beta, float invNs,
    short* __restrict__ Bp, float* __restrict__ biasOut)
{
    __shared__ float sS[128], sT[128];
    int tid = threadIdx.x;
    if (tid < 128) {
        float sum = 0.f, sq = 0.f;
        for (int r = 0; r < 16; r++) {
            sum += statsG[r * 256 + tid];
            sq  += statsG[r * 256 + 128 + tid];
        }
        float m = sum * invNs;
        float var = sq * invNs - m * m;
        float rs = rsqrtf(var + 1e-5f);
        float s = rs * gamma[tid];
        float t = beta[tid] - m * s;
        sS[tid] = s; sT[tid] = t;
    }
    __syncthreads();
    if (blockIdx.x == 0 && tid < 128) {
        float b = bias[tid];
        for (int k = 0; k < 128; k++) b += sT[k] * W[k * 128 + tid];
        biasOut[tid] = b;
    }
    int idx = blockIdx.x * 256 + tid;
    int n = idx >> 8, ks = (idx >> 6) & 3, lane = idx & 63;
    int k8 = ks * 32 + (lane >> 4) * 8;
    int pcol = (lane & 15) * 8 + n;
    bf16x8 fv;
    #pragma unroll
    for (int i2 = 0; i2 < 8; i2++)
        fv[i2] = f2bf(sS[k8 + i2] * W[(k8 + i2) * 128 + pcol]);
    *(bf16x8*)(Bp + (size_t)idx * 8) = fv;
}

// ---------------- counting sort by dst ----------------

__global__ __launch_bounds__(256) void hist_k(
    const int* __restrict__ dstI, int* __restrict__ cnt, int E)
{
    int e = blockIdx.x * 256 + threadIdx.x;
    if (e < E) atomicAdd(&cnt[dstI[e]], 1);
}

__global__ __launch_bounds__(256) void scan1_k(
    const int* __restrict__ cnt, int Nn, int* __restrict__ posE, int* __restrict__ bsum)
{
    __shared__ int s[256];
    int t = threadIdx.x, g = blockIdx.x * 256 + t;
    int v = (g < Nn) ? cnt[g] : 0;
    s[t] = v;
    __syncthreads();
    for (int off = 1; off < 256; off <<= 1) {
        int u = (t >= off) ? s[t - off] : 0;
        __syncthreads();
        s[t] += u;
        __syncthreads();
    }
    if (g < Nn) posE[g] = s[t] - v;
    if (t == 255) bsum[blockIdx.x] = s[255];
}

__global__ __launch_bounds__(256) void scan2_k(int* __restrict__ bsum, int nb)
{
    __shared__ int s[256];
    int t = threadIdx.x;
    int v = (t < nb) ? bsum[t] : 0;
    s[t] = v;
    __syncthreads();
    for (int off = 1; off < 256; off <<= 1) {
        int u = (t >= off) ? s[t - off] : 0;
        __syncthreads();
        s[t] += u;
        __syncthreads();
    }
    if (t < nb) bsum[t] = s[t] - v;
}

__global__ __launch_bounds__(256) void fix_k(
    const int* __restrict__ posE, const int* __restrict__ bsum,
    int* __restrict__ pos2, int Nn)
{
    int id = blockIdx.x * 256 + threadIdx.x;
    if (id < Nn) pos2[id] = posE[id] + bsum[id >> 8];
}

__global__ __launch_bounds__(256) void scat_k(
    const int* __restrict__ srcI, const int* __restrict__ dstI,
    const float4* __restrict__ ea4, int* __restrict__ pos2,
    int* __restrict__ sSrc, int* __restrict__ sDst,
    float* __restrict__ scf, float4* __restrict__ sEa, int E)
{
    int e = blockIdx.x * 256 + threadIdx.x;
    if (e >= E) return;
    int d = dstI[e];
    int p = atomicAdd(&pos2[d], 1);
    sSrc[p] = srcI[e];
    sDst[p] = d;
    float4 ev = ea4[e];
    sEa[p] = ev;
    scf[p] = cosf(1.57079632679f * ev.w);
}

// ---------------- fused node precompute: one A read, three B phases, no LDS ----------------
__global__ __launch_bounds__(256, 4) void node_all_k(
    const float* __restrict__ x, int M,
    const short* __restrict__ bp3,
    const float* __restrict__ bd, const float* __restrict__ vv,
    short* __restrict__ xd, short* __restrict__ zaccb,
    short* __restrict__ xs1b, short* __restrict__ xt1b)
{
    int tid = threadIdx.x;
    int wave = tid >> 6, lane = tid & 63;
    int kgrp = lane >> 4, colbase = lane & 15;
    int chunk = blockIdx.x;
    int rowA = chunk * 64 + wave * 16 + colbase;
    bool rv = rowA < M;

    bf16x8 af[4];
    #pragma unroll
    for (int ks = 0; ks < 4; ks++) {
        bf16x8 v = (bf16x8){0,0,0,0,0,0,0,0};
        if (rv) {
            const float* ap = x + (size_t)rowA * 128 + ks * 32 + kgrp * 8;
            float4 f0 = ((const float4*)ap)[0];
            float4 f1 = ((const float4*)ap)[1];
            v[0] = f2bf(f0.x); v[1] = f2bf(f0.y); v[2] = f2bf(f0.z); v[3] = f2bf(f0.w);
            v[4] = f2bf(f1.x); v[5] = f2bf(f1.y); v[6] = f2bf(f1.z); v[7] = f2bf(f1.w);
        }
        af[ks] = v;
    }

    float bcol[8], vcol[8];
    *(float4*)&bcol[0] = *(const float4*)(bd + colbase * 8);
    *(float4*)&bcol[4] = *(const float4*)(bd + colbase * 8 + 4);
    *(float4*)&vcol[0] = *(const float4*)(vv + colbase * 8);
    *(float4*)&vcol[4] = *(const float4*)(vv + colbase * 8 + 4);

    int rbase = chunk * 64 + wave * 16 + kgrp * 4;

    for (int b = 0; b < 3; b++) {
        const short* Bb = bp3 + (size_t)b * 16384;
        f32x4 acc[8];
        #pragma unroll
        for (int n = 0; n < 8; n++) acc[n] = (f32x4){0.f, 0.f, 0.f, 0.f};
        #pragma unroll
        for (int ks = 0; ks < 4; ks++) {
            #pragma unroll
            for (int n = 0; n < 8; n++) {
                bf16x8 bf = *(const bf16x8*)(Bb + ((size_t)((n * 4 + ks) * 64 + lane)) * 8);
                acc[n] = __builtin_amdgcn_mfma_f32_16x16x32_bf16(af[ks], bf, acc[n], 0, 0, 0);
            }
        }
        if (b == 0) {
            #pragma unroll
            for (int r = 0; r < 4; r++) {
                int row = rbase + r;
                if (row < M) {
                    bf16x8 xo, zo;
                    #pragma unroll
                    for (int n = 0; n < 8; n++) {
                        float val = acc[n][r] + bcol[n];
                        xo[n] = f2bf(val);
                        zo[n] = f2bf(vcol[n] * val);
                    }
                    *(bf16x8*)(xd    + (size_t)row * 128 + colbase * 8) = xo;
                    *(bf16x8*)(zaccb + (size_t)row * 128 + colbase * 8) = zo;
                }
            }
        } else {
            short* outp = (b == 1) ? xs1b : xt1b;
            #pragma unroll
            for (int r = 0; r < 4; r++) {
                int row = rbase + r;
                if (row < M) {
                    bf16x8 o;
                    #pragma unroll
                    for (int n = 0; n < 8; n++) o[n] = f2bf(acc[n][r]);
                    *(bf16x8*)(outp + (size_t)row * 128 + colbase * 8) = o;
                }
            }
        }
    }
}

// ---------------- edge pass 1 (sorted order, 2 cols/lane, 2-deep pipeline) ----------------
__global__ __launch_bounds__(256) void edge_z1_k(
    const short* __restrict__ xs1b, const short* __restrict__ xt1b,
    const short* __restrict__ tab,
    const int* __restrict__ sSrc, const int* __restrict__ sDst,
    const float4* __restrict__ sEa,
    short* __restrict__ z1, float* __restrict__ stats, int Etot)
{
    int tid = threadIdx.x, wave = tid >> 6, lane = tid & 63;
    int e0 = blockIdx.x * 256 + wave * 64;
    const unsigned* xs2 = (const unsigned*)xs1b;
    const unsigned* xt2 = (const unsigned*)xt1b;
    const unsigned* tb2 = (const unsigned*)tab;
    unsigned* z2 = (unsigned*)z1;

    int eL = e0 + lane;
    int myS = 0, myD = 0;
    float4 myE = {0.f, 0.f, 0.f, 0.f};
    if (eL < Etot) { myS = sSrc[eL]; myD = sDst[eL]; myE = sEa[eL]; }

    float s0 = 0.f, q0 = 0.f, s1 = 0.f, q1 = 0.f;
    int ni = Etot - e0; if (ni > 64) ni = 64;

    unsigned xsC = 0, xtC = 0, v0C[4], v1C[4];
    float fC[4];
    if (ni > 0) {
        int s = __shfl(myS, 0), d = __shfl(myD, 0);
        float tv[4];
        tv[0] = __shfl(myE.x, 0); tv[1] = __shfl(myE.y, 0);
        tv[2] = __shfl(myE.z, 0); tv[3] = __shfl(myE.w, 0);
        xsC = xs2[(size_t)s * 64 + lane];
        xtC = xt2[(size_t)d * 64 + lane];
        #pragma unroll
        for (int c = 0; c < 4; c++) {
            float u = tv[c] * 1024.f;
            int i0 = (int)u;
            if (i0 > 1023) i0 = 1023;
            if (i0 < 0) i0 = 0;
            fC[c] = u - (float)i0;
            size_t base = (size_t)(c * 1025 + i0) * 64 + lane;
            v0C[c] = tb2[base];
            v1C[c] = tb2[base + 64];
        }
    }

    for (int i = 0; i < ni; i++) {
        unsigned xsN = 0, xtN = 0, v0N[4], v1N[4];
        float fN[4];
        if (i + 1 < ni) {
            int s = __shfl(myS, i + 1), d = __shfl(myD, i + 1);
            float tv[4];
            tv[0] = __shfl(myE.x, i + 1); tv[1] = __shfl(myE.y, i + 1);
            tv[2] = __shfl(myE.z, i + 1); tv[3] = __shfl(myE.w, i + 1);
            xsN = xs2[(size_t)s * 64 + lane];
            xtN = xt2[(size_t)d * 64 + lane];
            #pragma unroll
            for (int c = 0; c < 4; c++) {
                float u = tv[c] * 1024.f;
                int i0 = (int)u;
                if (i0 > 1023) i0 = 1023;
                if (i0 < 0) i0 = 0;
                fN[c] = u - (float)i0;
                size_t base = (size_t)(c * 1025 + i0) * 64 + lane;
                v0N[c] = tb2[base];
                v1N[c] = tb2[base + 64];
            }
        }
        float2 xs = bfpair(xsC);
        float2 xt = bfpair(xtC);
        float p0 = xs.x + xt.x, p1 = xs.y + xt.y;
        #pragma unroll
        for (int c = 0; c < 4; c++) {
            float2 v0 = bfpair(v0C[c]);
            float2 v1 = bfpair(v1C[c]);
            p0 += v0.x + fC[c] * (v1.x - v0.x);
            p1 += v0.y + fC[c] * (v1.y - v0.y);
        }
        float z0 = p0 >= 0.f ? p0 : 0.01f * p0;
        float z1v = p1 >= 0.f ? p1 : 0.01f * p1;
        z2[(size_t)(e0 + i) * 64 + lane] = packbf(z0, z1v);
        s0 += z0; q0 += z0 * z0; s1 += z1v; q1 += z1v * z1v;

        xsC = xsN; xtC = xtN;
        #pragma unroll
        for (int c = 0; c < 4; c++) { v0C[c] = v0N[c]; v1C[c] = v1N[c]; fC[c] = fN[c]; }
    }

    __shared__ float lS[128], lQ[128];
    if (tid < 128) { lS[tid] = 0.f; lQ[tid] = 0.f; }
    __syncthreads();
    atomicAdd(&lS[2 * lane], s0);     atomicAdd(&lS[2 * lane + 1], s1);
    atomicAdd(&lQ[2 * lane], q0);     atomicAdd(&lQ[2 * lane + 1], q1);
    __syncthreads();
    if (tid < 128) {
        int rep = blockIdx.x & 15;
        atomicAdd(&stats[rep * 256 + tid], lS[tid]);
        atomicAdd(&stats[rep * 256 + 128 + tid], lQ[tid]);
    }
}

// ---------------- tall-skinny MFMA GEMM, B direct from global, no barrier ----------------
// EPI 2: z=lrelu(val); out bf16 (16B/lane); BN stats (1KB LDS)
// EPI 3: dst-sorted scatter: run-merged pk_add_bf16(zacc[dst], cf*val*xd[src])
// EPI 4: out fp32 = val + xres (two float4/lane)
template<int EPI>
__global__ __launch_bounds__(256, 4) void pgemm_k(
    const short* __restrict__ A, int M,
    const short* __restrict__ Bp, const float* __restrict__ bias,
    void* __restrict__ out, float* __restrict__ stats,
    const short* __restrict__ xd, short* __restrict__ zaccb,
    const float* __restrict__ scf, const int* __restrict__ sSrc,
    const int* __restrict__ sDst, const float* __restrict__ xres)
{
    int tid = threadIdx.x;
    int wave = tid >> 6, lane = tid & 63;
    int kgrp = lane >> 4, colbase = lane & 15;
    int chunk = blockIdx.x;
    int rowA = chunk * 64 + wave * 16 + colbase;
    bool rv = rowA < M;

    bf16x8 af[4];
    #pragma unroll
    for (int ks = 0; ks < 4; ks++)
        af[ks] = rv ? *(const bf16x8*)(A + (size_t)rowA * 128 + ks * 32 + kgrp * 8)
                    : (bf16x8){0,0,0,0,0,0,0,0};

    int rbase = chunk * 64 + wave * 16 + kgrp * 4;

    int mdst[4], msx[4]; float mcf[4];
    bf16x8 xg[4];
    if (EPI == 3) {
        #pragma unroll
        for (int r = 0; r < 4; r++) {
            int row = rbase + r; bool ok = row < M;
            mdst[r] = ok ? sDst[row] : -1;
            msx[r]  = ok ? sSrc[row] : 0;
            mcf[r]  = ok ? scf[row] : 0.f;
        }
        #pragma unroll
        for (int r = 0; r < 4; r++)
            xg[r] = (mdst[r] >= 0)
                ? *(const bf16x8*)(xd + (size_t)msx[r] * 128 + colbase * 8)
                : (bf16x8){0,0,0,0,0,0,0,0};
    }

    float bcol[8];
    *(float4*)&bcol[0] = *(const float4*)(bias + colbase * 8);
    *(float4*)&bcol[4] = *(const float4*)(bias + colbase * 8 + 4);

    f32x4 acc[8];
    #pragma unroll
    for (int n = 0; n < 8; n++) acc[n] = (f32x4){0.f, 0.f, 0.f, 0.f};
    #pragma unroll
    for (int ks = 0; ks < 4; ks++) {
        #pragma unroll
        for (int n = 0; n < 8; n++) {
            bf16x8 bf = *(const bf16x8*)(Bp + ((size_t)((n * 4 + ks) * 64 + lane)) * 8);
            acc[n] = __builtin_amdgcn_mfma_f32_16x16x32_bf16(af[ks], bf, acc[n], 0, 0, 0);
        }
    }

    if (EPI == 2) {
        __shared__ float lS[128], lQ[128];
        float sreg[8], qreg[8];
        #pragma unroll
        for (int n = 0; n < 8; n++) { sreg[n] = 0.f; qreg[n] = 0.f; }
        short* outh = (short*)out;
        #pragma unroll
        for (int r = 0; r < 4; r++) {
            int row = rbase + r;
            bf16x8 o;
            #pragma unroll
            for (int n = 0; n < 8; n++) {
                float z = acc[n][r] + bcol[n];
                z = z >= 0.f ? z : 0.01f * z;
                if (row >= M) z = 0.f;
                sreg[n] += z; qreg[n] += z * z;
                o[n] = f2bf(z);
            }
            if (row < M)
                *(bf16x8*)(outh + (size_t)row * 128 + colbase * 8) = o;
        }
        if (tid < 128) { lS[tid] = 0.f; lQ[tid] = 0.f; }
        __syncthreads();
        #pragma unroll
        for (int n = 0; n < 8; n++) {
            atomicAdd(&lS[colbase * 8 + n], sreg[n]);
            atomicAdd(&lQ[colbase * 8 + n], qreg[n]);
        }
        __syncthreads();
        if (tid < 128) {
            int rep = blockIdx.x & 15;
            atomicAdd(&stats[rep * 256 + tid], lS[tid]);
            atomicAdd(&stats[rep * 256 + 128 + tid], lQ[tid]);
        }
    } else if (EPI == 3) {
        #pragma unroll
        for (int np = 0; np < 4; np++) {
            float ra = 0.f, rb = 0.f;
            int curd = mdst[0];
            #pragma unroll
            for (int r = 0; r < 4; r++) {
                float ma = 0.f, mb = 0.f;
                if (mdst[r] >= 0) {
                    float va = acc[2 * np][r] + bcol[2 * np];
                    float vb = acc[2 * np + 1][r] + bcol[2 * np + 1];
                    ma = mcf[r] * va * bf2f(xg[r][2 * np]);
                    mb = mcf[r] * vb * bf2f(xg[r][2 * np + 1]);
                }
                if (mdst[r] != curd) {
                    if (curd >= 0) {
                        unsigned packed = packbf(ra, rb);
                        short* ap = zaccb + (size_t)curd * 128 + colbase * 8 + 2 * np;
                        asm volatile("global_atomic_pk_add_bf16 %0, %1, off"
                                     :: "v"(ap), "v"(packed) : "memory");
                    }
                    ra = 0.f; rb = 0.f; curd = mdst[r];
                }
                ra += ma; rb += mb;
            }
            if (curd >= 0) {
                unsigned packed = packbf(ra, rb);
                short* ap = zaccb + (size_t)curd * 128 + colbase * 8 + 2 * np;
                asm volatile("global_atomic_pk_add_bf16 %0, %1, off"
                             :: "v"(ap), "v"(packed) : "memory");
            }
        }
    } else if (EPI == 4) {
        float* outf = (float*)out;
        #pragma unroll
        for (int r = 0; r < 4; r++) {
            int row = rbase + r;
            if (row < M) {
                const float4* xr = (const float4*)(xres + (size_t)row * 128 + colbase * 8);
                float4 x0 = xr[0], x1 = xr[1];
                float4 o0, o1;
                o0.x = acc[0][r] + bcol[0] + x0.x;
                o0.y = acc[1][r] + bcol[1] + x0.y;
                o0.z = acc[2][r] + bcol[2] + x0.z;
                o0.w = acc[3][r] + bcol[3] + x0.w;
                o1.x = acc[4][r] + bcol[4] + x1.x;
                o1.y = acc[5][r] + bcol[5] + x1.y;
                o1.z = acc[6][r] + bcol[6] + x1.z;
                o1.w = acc[7][r] + bcol[7] + x1.w;
                float4* op = (float4*)(outf + (size_t)row * 128 + colbase * 8);
                op[0] = o0; op[1] = o1;
            }
        }
    }
}

extern "C" void kernel_launch(void* const* d_in, const int* in_sizes, int n_in,
                              void* d_out, int out_size, void* d_ws, size_t ws_size,
                              hipStream_t stream)
{
    const float* x    = (const float*)d_in[0];
    const float* ea   = (const float*)d_in[1];
    const int*   eidx = (const int*)d_in[2];
    const float* Wb   = (const float*)d_in[3];
    const float* bb   = (const float*)d_in[4];
    const float* We1  = (const float*)d_in[5];
    const float* be1  = (const float*)d_in[6];
    const float* ge1  = (const float*)d_in[7];
    const float* bte1 = (const float*)d_in[8];
    const float* We2  = (const float*)d_in[9];
    const float* be2  = (const float*)d_in[10];
    const float* ge2  = (const float*)d_in[11];
    const float* bte2 = (const float*)d_in[12];
    const float* We3  = (const float*)d_in[13];
    const float* be3  = (const float*)d_in[14];
    const float* Wd   = (const float*)d_in[15];
    const float* bd   = (const float*)d_in[16];
    const float* vv   = (const float*)d_in[17];
    const float* Wn1  = (const float*)d_in[18];
    const float* bn1  = (const float*)d_in[19];
    const float* gn   = (const float*)d_in[20];
    const float* btn  = (const float*)d_in[21];
    const float* Wn2  = (const float*)d_in[22];
    const float* bn2  = (const float*)d_in[23];

    const int NN = in_sizes[0] / 128;   // 50000
    const int EE = in_sizes[1] / 4;     // 300000

    char* ws = (char*)d_ws;
    size_t oEZ   = 0;
    size_t oXD   = oEZ   + (size_t)EE * 256;
    size_t oXS   = oXD   + (size_t)NN * 256;
    size_t oXT   = oXS   + (size_t)NN * 256;
    size_t oZACC = oXT   + (size_t)NN * 256;
    size_t oZN   = oZACC + (size_t)NN * 256;
    size_t oTAB  = oZN   + (size_t)NN * 256;
    size_t oW1P  = oTAB  + (size_t)4 * 1025 * 256;
    size_t oB1P  = oW1P  + (size_t)200 * 512;
    size_t oBP   = oB1P  + 512;
    size_t oBIAS = oBP   + (size_t)7 * 32768;
    size_t oST   = oBIAS + (size_t)7 * 512;
    size_t oCNT  = oST   + 49152;
    size_t oPOS  = oCNT  + 201728;
    size_t oBSUM = oPOS  + 201728;
    size_t oPOS2 = oBSUM + 1024;
    size_t oSSRC = oPOS2 + 201728;
    size_t oSDST = oSSRC + (size_t)EE * 4;
    size_t oSCF  = oSDST + (size_t)EE * 4;
    size_t oSEA  = (oSCF + (size_t)EE * 4 + 15) & ~(size_t)15;

    short* eZ    = (short*)(ws + oEZ);
    short* xd    = (short*)(ws + oXD);
    short* xs1b  = (short*)(ws + oXS);
    short* xt1b  = (short*)(ws + oXT);
    short* zaccb = (short*)(ws + oZACC);
    short* zn    = (short*)(ws + oZN);
    short* tab   = (short*)(ws + oTAB);
    float* W1p   = (float*)(ws + oW1P);
    float* b1p   = (float*)(ws + oB1P);
    short* bp    = (short*)(ws + oBP);
    short* BpW2  = bp + 3 * 16384;
    short* BpW3  = bp + 4 * 16384;
    short* BpN1  = bp + 5 * 16384;
    short* BpN2  = bp + 6 * 16384;
    float* bo    = (float*)(ws + oBIAS);
    float* b2p   = bo + 0 * 128;
    float* b3p   = bo + 1 * 128;
    float* b2np  = bo + 2 * 128;
    float* st1   = (float*)(ws + oST);
    float* st2   = st1 + 4096;
    float* stN   = st1 + 8192;
    int*   cnt   = (int*)(ws + oCNT);
    int*   posE  = (int*)(ws + oPOS);
    int*   bsum  = (int*)(ws + oBSUM);
    int*   pos2  = (int*)(ws + oPOS2);
    int*   sSrc  = (int*)(ws + oSSRC);
    int*   sDst  = (int*)(ws + oSDST);
    float* scf   = (float*)(ws + oSCF);
    float4* sEa  = (float4*)(ws + oSEA);

    hipMemsetAsync(ws + oST, 0, 49152 + 201728, stream);

    build_w1p_k<<<201, 128, 0, stream>>>(Wb, We1, bb, be1, W1p, b1p);
    build_tab_k<<<dim3(1025, 4), 128, 0, stream>>>(W1p, b1p, tab);
    fold_plain_k<<<dim3(8, 4), 256, 0, stream>>>(
        Wd, We1, We1 + 256 * 128, Wn1, bp, bp + 16384, bp + 2 * 16384, BpN1);

    int nchN = (NN + 63) / 64;
    int nchE = (EE + 63) / 64;
    int nbN = (NN + 255) / 256;
    int nbE = (EE + 255) / 256;

    // fused node precompute: xd/zacc, xs1, xt1  (reads x once)
    node_all_k<<<nchN, 256, 0, stream>>>(x, NN, bp, bd, vv, xd, zaccb, xs1b, xt1b);

    // counting sort by dst
    hist_k<<<nbE, 256, 0, stream>>>(eidx + EE, cnt, EE);
    scan1_k<<<nbN, 256, 0, stream>>>(cnt, NN, posE, bsum);
    scan2_k<<<1, 256, 0, stream>>>(bsum, nbN);
    fix_k<<<nbN, 256, 0, stream>>>(posE, bsum, pos2, NN);
    scat_k<<<nbE, 256, 0, stream>>>(eidx, eidx + EE, (const float4*)ea, pos2,
                                    sSrc, sDst, scf, sEa, EE);

    edge_z1_k<<<nbE, 256, 0, stream>>>(xs1b, xt1b, tab, sSrc, sDst, sEa, eZ, st1, EE);

    fold_k<<<8, 256, 0, stream>>>(We2, be2, st1, ge1, bte1, 1.f / (float)EE, BpW2, b2p);
    pgemm_k<2><<<nchE, 256, 0, stream>>>(eZ, EE, BpW2, b2p, eZ, st2,
        nullptr, nullptr, nullptr, nullptr, nullptr, nullptr);

    fold_k<<<8, 256, 0, stream>>>(We3, be3, st2, ge2, bte2, 1.f / (float)EE, BpW3, b3p);
    pgemm_k<3><<<nchE, 256, 0, stream>>>(eZ, EE, BpW3, b3p, nullptr, nullptr,
        xd, zaccb, scf, sSrc, sDst, nullptr);

    pgemm_k<2><<<nchN, 256, 0, stream>>>(zaccb, NN, BpN1, bn1, zn, stN,
        nullptr, nullptr, nullptr, nullptr, nullptr, nullptr);

    fold_k<<<8, 256, 0, stream>>>(Wn2, bn2, stN, gn, btn, 1.f / (float)NN, BpN2, b2np);
    pgemm_k<4><<<nchN, 256, 0, stream>>>(zn, NN, BpN2, b2np, d_out, nullptr,
        nullptr, nullptr, nullptr, nullptr, nullptr, x);
}

// Round 9
// 494.414 us; speedup vs baseline: 1.1339x; 1.1339x over previous
//
#include <hip/hip_runtime.h>

typedef __attribute__((ext_vector_type(8))) short bf16x8;
typedef __attribute__((ext_vector_type(4))) float f32x4;

#define DEVFN __device__ __forceinline__

DEVFN short f2bf(float f) {
    union { float f; unsigned u; } v; v.f = f;
    unsigned r = (v.u + 0x7FFFu + ((v.u >> 16) & 1u)) >> 16;
    return (short)(unsigned short)r;
}
DEVFN float bf2f(short h) {
    union { unsigned u; float f; } v; v.u = ((unsigned)(unsigned short)h) << 16;
    return v.f;
}
DEVFN unsigned packbf(float a, float b) {
    return (unsigned)(unsigned short)f2bf(a) | ((unsigned)(unsigned short)f2bf(b) << 16);
}

// async global->LDS, 16B per lane. lds dst must be wave-uniform-base + lane*16.
#define GLD_LDS16(gp, lp)                                                     \
    __builtin_amdgcn_global_load_lds(                                         \
        (const __attribute__((address_space(1))) unsigned*)(gp),              \
        (__attribute__((address_space(3))) unsigned*)(lp), 16, 0, 0)

// Column permutation folded into weights: MFMA col c computes original col
// P(c) = (c&15)*8 + (c>>4); lane owns contiguous cols colbase*8..+7.

// ---------------- prep kernels ----------------

__global__ __launch_bounds__(128) void build_w1p_k(
    const float* __restrict__ Wb, const float* __restrict__ We1,
    const float* __restrict__ bb, const float* __restrict__ be1,
    float* __restrict__ W1p, float* __restrict__ b1p)
{
    int j = threadIdx.x;
    const float* B = We1 + 128 * 128;
    int i = blockIdx.x;
    if (i < 200) {
        float a = 0.f;
        for (int m = 0; m < 128; m++) a += Wb[i * 128 + m] * B[m * 128 + j];
        W1p[i * 128 + j] = a;
    } else {
        float a = be1[j];
        for (int m = 0; m < 128; m++) a += bb[m] * B[m * 128 + j];
        b1p[j] = a;
    }
}

__global__ __launch_bounds__(128) void build_tab_k(
    const float* __restrict__ W1p, const float* __restrict__ b1p,
    short* __restrict__ tab)
{
    int i = blockIdx.x;   // 0..1024
    int c = blockIdx.y;   // 0..3
    int j = threadIdx.x;
    float t = (float)i * (1.0f / 1024.0f);
    float acc = (c == 0) ? b1p[j] : 0.f;
    int kc = (int)(t * 49.f + 0.5f);
    for (int dk = -6; dk <= 6; dk++) {
        int k = kc + dk;
        if (k >= 0 && k < 50) {
            float d = t - (float)k * (1.f / 49.f);
            float g = expf(-1250.f * d * d);
            acc += g * W1p[(c * 50 + k) * 128 + j];
        }
    }
    tab[((size_t)(c * 1025 + i)) * 128 + j] = f2bf(acc);
}

__global__ __launch_bounds__(256) void fold_plain_k(
    const float* __restrict__ W0, const float* __restrict__ W1,
    const float* __restrict__ W2, const float* __restrict__ W3,
    short* __restrict__ O0, short* __restrict__ O1,
    short* __restrict__ O2, short* __restrict__ O3)
{
    const float* W = (blockIdx.y == 0) ? W0 : (blockIdx.y == 1) ? W1 : (blockIdx.y == 2) ? W2 : W3;
    short* O = (blockIdx.y == 0) ? O0 : (blockIdx.y == 1) ? O1 : (blockIdx.y == 2) ? O2 : O3;
    int idx = blockIdx.x * 256 + threadIdx.x;
    int n = idx >> 8, ks = (idx >> 6) & 3, lane = idx & 63;
    int k8 = ks * 32 + (lane >> 4) * 8;
    int pcol = (lane & 15) * 8 + n;              // P(n*16 + colbase)
    bf16x8 fv;
    #pragma unroll
    for (int i2 = 0; i2 < 8; i2++) fv[i2] = f2bf(W[(k8 + i2) * 128 + pcol]);
    *(bf16x8*)(O + (size_t)idx * 8) = fv;
}

__global__ __launch_bounds__(256) void fold_k(
    const float* __restrict__ W, const float* __restrict__ bias,
    const float* __restrict__ statsG, const float* __restrict__ gamma,
    const float* __restrict__ beta, float invNs,
    short* __restrict__ Bp, float* __restrict__ biasOut)
{
    __shared__ float sS[128], sT[128];
    int tid = threadIdx.x;
    if (tid < 128) {
        float sum = 0.f, sq = 0.f;
        for (int r = 0; r < 16; r++) {
            sum += statsG[r * 256 + tid];
            sq  += statsG[r * 256 + 128 + tid];
        }
        float m = sum * invNs;
        float var = sq * invNs - m * m;
        float rs = rsqrtf(var + 1e-5f);
        float s = rs * gamma[tid];
        float t = beta[tid] - m * s;
        sS[tid] = s; sT[tid] = t;
    }
    __syncthreads();
    if (blockIdx.x == 0 && tid < 128) {
        float b = bias[tid];
        for (int k = 0; k < 128; k++) b += sT[k] * W[k * 128 + tid];
        biasOut[tid] = b;
    }
    int idx = blockIdx.x * 256 + tid;
    int n = idx >> 8, ks = (idx >> 6) & 3, lane = idx & 63;
    int k8 = ks * 32 + (lane >> 4) * 8;
    int pcol = (lane & 15) * 8 + n;
    bf16x8 fv;
    #pragma unroll
    for (int i2 = 0; i2 < 8; i2++)
        fv[i2] = f2bf(sS[k8 + i2] * W[(k8 + i2) * 128 + pcol]);
    *(bf16x8*)(Bp + (size_t)idx * 8) = fv;
}

// ---------------- counting sort by dst ----------------

__global__ __launch_bounds__(256) void hist_k(
    const int* __restrict__ dstI, int* __restrict__ cnt, int E)
{
    int e = blockIdx.x * 256 + threadIdx.x;
    if (e < E) atomicAdd(&cnt[dstI[e]], 1);
}

__global__ __launch_bounds__(256) void scan1_k(
    const int* __restrict__ cnt, int Nn, int* __restrict__ posE, int* __restrict__ bsum)
{
    __shared__ int s[256];
    int t = threadIdx.x, g = blockIdx.x * 256 + t;
    int v = (g < Nn) ? cnt[g] : 0;
    s[t] = v;
    __syncthreads();
    for (int off = 1; off < 256; off <<= 1) {
        int u = (t >= off) ? s[t - off] : 0;
        __syncthreads();
        s[t] += u;
        __syncthreads();
    }
    if (g < Nn) posE[g] = s[t] - v;
    if (t == 255) bsum[blockIdx.x] = s[255];
}

__global__ __launch_bounds__(256) void scan2_k(int* __restrict__ bsum, int nb)
{
    __shared__ int s[256];
    int t = threadIdx.x;
    int v = (t < nb) ? bsum[t] : 0;
    s[t] = v;
    __syncthreads();
    for (int off = 1; off < 256; off <<= 1) {
        int u = (t >= off) ? s[t - off] : 0;
        __syncthreads();
        s[t] += u;
        __syncthreads();
    }
    if (t < nb) bsum[t] = s[t] - v;
}

__global__ __launch_bounds__(256) void fix_k(
    const int* __restrict__ posE, const int* __restrict__ bsum,
    int* __restrict__ pos2, int Nn)
{
    int id = blockIdx.x * 256 + threadIdx.x;
    if (id < Nn) pos2[id] = posE[id] + bsum[id >> 8];
}

__global__ __launch_bounds__(256) void scat_k(
    const int* __restrict__ srcI, const int* __restrict__ dstI,
    const float4* __restrict__ ea4, int* __restrict__ pos2,
    int* __restrict__ sSrc, int* __restrict__ sDst,
    float* __restrict__ scf, float4* __restrict__ sEa, int E)
{
    int e = blockIdx.x * 256 + threadIdx.x;
    if (e >= E) return;
    int d = dstI[e];
    int p = atomicAdd(&pos2[d], 1);
    sSrc[p] = srcI[e];
    sDst[p] = d;
    float4 ev = ea4[e];
    sEa[p] = ev;
    scf[p] = cosf(1.57079632679f * ev.w);
}

// ---------------- fused node precompute (direct-global B, small grid) ----------------
__global__ __launch_bounds__(256, 4) void node_all_k(
    const float* __restrict__ x, int M,
    const short* __restrict__ bp3,
    const float* __restrict__ bd, const float* __restrict__ vv,
    short* __restrict__ xd, short* __restrict__ zaccb,
    short* __restrict__ xs1b, short* __restrict__ xt1b)
{
    int tid = threadIdx.x;
    int wave = tid >> 6, lane = tid & 63;
    int kgrp = lane >> 4, colbase = lane & 15;
    int chunk = blockIdx.x;
    int rowA = chunk * 64 + wave * 16 + colbase;
    bool rv = rowA < M;

    bf16x8 af[4];
    #pragma unroll
    for (int ks = 0; ks < 4; ks++) {
        bf16x8 v = (bf16x8){0,0,0,0,0,0,0,0};
        if (rv) {
            const float* ap = x + (size_t)rowA * 128 + ks * 32 + kgrp * 8;
            float4 f0 = ((const float4*)ap)[0];
            float4 f1 = ((const float4*)ap)[1];
            v[0] = f2bf(f0.x); v[1] = f2bf(f0.y); v[2] = f2bf(f0.z); v[3] = f2bf(f0.w);
            v[4] = f2bf(f1.x); v[5] = f2bf(f1.y); v[6] = f2bf(f1.z); v[7] = f2bf(f1.w);
        }
        af[ks] = v;
    }

    float bcol[8], vcol[8];
    *(float4*)&bcol[0] = *(const float4*)(bd + colbase * 8);
    *(float4*)&bcol[4] = *(const float4*)(bd + colbase * 8 + 4);
    *(float4*)&vcol[0] = *(const float4*)(vv + colbase * 8);
    *(float4*)&vcol[4] = *(const float4*)(vv + colbase * 8 + 4);

    int rbase = chunk * 64 + wave * 16 + kgrp * 4;

    for (int b = 0; b < 3; b++) {
        const short* Bb = bp3 + (size_t)b * 16384;
        f32x4 acc[8];
        #pragma unroll
        for (int n = 0; n < 8; n++) acc[n] = (f32x4){0.f, 0.f, 0.f, 0.f};
        #pragma unroll
        for (int ks = 0; ks < 4; ks++) {
            #pragma unroll
            for (int n = 0; n < 8; n++) {
                bf16x8 bf = *(const bf16x8*)(Bb + ((size_t)((n * 4 + ks) * 64 + lane)) * 8);
                acc[n] = __builtin_amdgcn_mfma_f32_16x16x32_bf16(af[ks], bf, acc[n], 0, 0, 0);
            }
        }
        if (b == 0) {
            #pragma unroll
            for (int r = 0; r < 4; r++) {
                int row = rbase + r;
                if (row < M) {
                    bf16x8 xo, zo;
                    #pragma unroll
                    for (int n = 0; n < 8; n++) {
                        float val = acc[n][r] + bcol[n];
                        xo[n] = f2bf(val);
                        zo[n] = f2bf(vcol[n] * val);
                    }
                    *(bf16x8*)(xd    + (size_t)row * 128 + colbase * 8) = xo;
                    *(bf16x8*)(zaccb + (size_t)row * 128 + colbase * 8) = zo;
                }
            }
        } else {
            short* outp = (b == 1) ? xs1b : xt1b;
            #pragma unroll
            for (int r = 0; r < 4; r++) {
                int row = rbase + r;
                if (row < M) {
                    bf16x8 o;
                    #pragma unroll
                    for (int n = 0; n < 8; n++) o[n] = f2bf(acc[n][r]);
                    *(bf16x8*)(outp + (size_t)row * 128 + colbase * 8) = o;
                }
            }
        }
    }
}

// ---------------- edge pass 1: 4 edges/step, 16B/lane loads ----------------
// lane = esub(2b) x colgroup(4b): lane handles edge e0+st*4+esub, cols colg*8..+7
__global__ __launch_bounds__(256) void edge_z1_k(
    const short* __restrict__ xs1b, const short* __restrict__ xt1b,
    const short* __restrict__ tab,
    const int* __restrict__ sSrc, const int* __restrict__ sDst,
    const float4* __restrict__ sEa,
    short* __restrict__ z1, float* __restrict__ stats, int Etot)
{
    int tid = threadIdx.x, wave = tid >> 6, lane = tid & 63;
    int colg = lane & 15, esub = lane >> 4;
    int e0 = blockIdx.x * 256 + wave * 64;

    int eL = e0 + lane;
    int myS = 0, myD = 0;
    float4 myE = {0.f, 0.f, 0.f, 0.f};
    if (eL < Etot) { myS = sSrc[eL]; myD = sDst[eL]; myE = sEa[eL]; }

    float sacc[8], qacc[8];
    #pragma unroll
    for (int j = 0; j < 8; j++) { sacc[j] = 0.f; qacc[j] = 0.f; }

    int ni = Etot - e0; if (ni > 64) ni = 64;
    int nsteps = (ni + 3) >> 2;

    for (int st = 0; st < nsteps; st++) {
        int i = st * 4 + esub;                 // edge slot within wave (0..63)
        bool valid = i < ni;
        int s = __shfl(myS, i);
        int d = __shfl(myD, i);
        float tv[4];
        tv[0] = __shfl(myE.x, i); tv[1] = __shfl(myE.y, i);
        tv[2] = __shfl(myE.z, i); tv[3] = __shfl(myE.w, i);

        bf16x8 xs8 = *(const bf16x8*)(xs1b + (size_t)s * 128 + colg * 8);
        bf16x8 xt8 = *(const bf16x8*)(xt1b + (size_t)d * 128 + colg * 8);

        float p[8];
        #pragma unroll
        for (int j = 0; j < 8; j++) p[j] = bf2f(xs8[j]) + bf2f(xt8[j]);

        #pragma unroll
        for (int c = 0; c < 4; c++) {
            float u = tv[c] * 1024.f;
            int i0 = (int)u;
            if (i0 > 1023) i0 = 1023;
            if (i0 < 0) i0 = 0;
            float f = u - (float)i0;
            const short* tb = tab + ((size_t)(c * 1025 + i0)) * 128 + colg * 8;
            bf16x8 t0 = *(const bf16x8*)tb;
            bf16x8 t1 = *(const bf16x8*)(tb + 128);
            #pragma unroll
            for (int j = 0; j < 8; j++) {
                float v0 = bf2f(t0[j]);
                p[j] += v0 + f * (bf2f(t1[j]) - v0);
            }
        }

        bf16x8 o;
        #pragma unroll
        for (int j = 0; j < 8; j++) {
            float z = p[j] >= 0.f ? p[j] : 0.01f * p[j];
            o[j] = f2bf(z);
            if (valid) { sacc[j] += z; qacc[j] += z * z; }
        }
        if (valid)
            *(bf16x8*)(z1 + (size_t)(e0 + i) * 128 + colg * 8) = o;
    }

    __shared__ float lS[128], lQ[128];
    if (tid < 128) { lS[tid] = 0.f; lQ[tid] = 0.f; }
    __syncthreads();
    #pragma unroll
    for (int j = 0; j < 8; j++) {
        atomicAdd(&lS[colg * 8 + j], sacc[j]);
        atomicAdd(&lQ[colg * 8 + j], qacc[j]);
    }
    __syncthreads();
    if (tid < 128) {
        int rep = blockIdx.x & 15;
        atomicAdd(&stats[rep * 256 + tid], lS[tid]);
        atomicAdd(&stats[rep * 256 + 128 + tid], lQ[tid]);
    }
}

// ---------------- NB=4 MFMA GEMM: async-LDS B, deep A prefetch, 1 barrier ----------------
// EPI 2: z=lrelu(val); out bf16; BN stats
// EPI 3: dst-sorted scatter: run-merged pk_add_bf16(zacc[dst], cf*val*xd[src])
// EPI 4: out fp32 = val + xres
template<int EPI>
__global__ __launch_bounds__(256, 2) void pgemm_k(
    const short* __restrict__ A, int M,
    const short* __restrict__ Bp, const float* __restrict__ bias,
    void* __restrict__ out, float* __restrict__ stats,
    const short* __restrict__ xd, short* __restrict__ zaccb,
    const float* __restrict__ scf, const int* __restrict__ sSrc,
    const int* __restrict__ sDst, const float* __restrict__ xres)
{
    __shared__ __align__(16) short ldsB[16384];
    __shared__ float lS[128], lQ[128];
    int tid = threadIdx.x;
    int wave = tid >> 6, lane = tid & 63;
    int kgrp = lane >> 4, colbase = lane & 15;

    // async stage B -> LDS: 8 issues x (4 waves x 64 lanes x 16B) = 32KB
    #pragma unroll
    for (int i = 0; i < 8; i++) {
        int off = (i * 256 + wave * 64 + lane) * 8;   // shorts; lane-contiguous
        GLD_LDS16(Bp + off, ldsB + off);
    }

    int c0 = blockIdx.x * 4;
    // deep A prefetch: all 16 fragments (16KB/wave in flight)
    bf16x8 af[4][4];
    #pragma unroll
    for (int j = 0; j < 4; j++) {
        int rowA = (c0 + j) * 64 + wave * 16 + colbase;
        bool rv = rowA < M;
        #pragma unroll
        for (int ks = 0; ks < 4; ks++)
            af[j][ks] = rv ? *(const bf16x8*)(A + (size_t)rowA * 128 + ks * 32 + kgrp * 8)
                           : (bf16x8){0,0,0,0,0,0,0,0};
    }

    float bcol[8];
    *(float4*)&bcol[0] = *(const float4*)(bias + colbase * 8);
    *(float4*)&bcol[4] = *(const float4*)(bias + colbase * 8 + 4);

    float sreg[8], qreg[8];
    if (EPI == 2) {
        #pragma unroll
        for (int n = 0; n < 8; n++) { sreg[n] = 0.f; qreg[n] = 0.f; }
        if (tid < 128) { lS[tid] = 0.f; lQ[tid] = 0.f; }
    }

    __syncthreads();   // B staged (drains A prefetch too -- once per 4 chunks)

    #pragma unroll
    for (int j = 0; j < 4; j++) {
        int chunk = c0 + j;
        if (chunk * 64 >= M) break;
        int rbase = chunk * 64 + wave * 16 + kgrp * 4;

        int mdst[4]; float mcf[4];
        bf16x8 xg[4];
        if (EPI == 3) {
            #pragma unroll
            for (int r = 0; r < 4; r++) {
                int row = rbase + r; bool ok = row < M;
                mdst[r] = ok ? sDst[row] : -1;
                int sx   = ok ? sSrc[row] : 0;
                mcf[r]  = ok ? scf[row] : 0.f;
                xg[r] = ok ? *(const bf16x8*)(xd + (size_t)sx * 128 + colbase * 8)
                           : (bf16x8){0,0,0,0,0,0,0,0};
            }
        }

        f32x4 acc[8];
        #pragma unroll
        for (int n = 0; n < 8; n++) acc[n] = (f32x4){0.f, 0.f, 0.f, 0.f};
        #pragma unroll
        for (int ks = 0; ks < 4; ks++) {
            #pragma unroll
            for (int n = 0; n < 8; n++) {
                bf16x8 bf = *(const bf16x8*)(ldsB + ((size_t)((n * 4 + ks) * 64 + lane)) * 8);
                acc[n] = __builtin_amdgcn_mfma_f32_16x16x32_bf16(af[j][ks], bf, acc[n], 0, 0, 0);
            }
        }

        if (EPI == 2) {
            short* outh = (short*)out;
            #pragma unroll
            for (int r = 0; r < 4; r++) {
                int row = rbase + r;
                bf16x8 o;
                #pragma unroll
                for (int n = 0; n < 8; n++) {
                    float z = acc[n][r] + bcol[n];
                    z = z >= 0.f ? z : 0.01f * z;
                    if (row >= M) z = 0.f;
                    sreg[n] += z; qreg[n] += z * z;
                    o[n] = f2bf(z);
                }
                if (row < M)
                    *(bf16x8*)(outh + (size_t)row * 128 + colbase * 8) = o;
            }
        } else if (EPI == 3) {
            #pragma unroll
            for (int np = 0; np < 4; np++) {
                float ra = 0.f, rb = 0.f;
                int curd = mdst[0];
                #pragma unroll
                for (int r = 0; r < 4; r++) {
                    float ma = 0.f, mb = 0.f;
                    if (mdst[r] >= 0) {
                        float va = acc[2 * np][r] + bcol[2 * np];
                        float vb = acc[2 * np + 1][r] + bcol[2 * np + 1];
                        ma = mcf[r] * va * bf2f(xg[r][2 * np]);
                        mb = mcf[r] * vb * bf2f(xg[r][2 * np + 1]);
                    }
                    if (mdst[r] != curd) {
                        if (curd >= 0) {
                            unsigned packed = packbf(ra, rb);
                            short* ap = zaccb + (size_t)curd * 128 + colbase * 8 + 2 * np;
                            asm volatile("global_atomic_pk_add_bf16 %0, %1, off"
                                         :: "v"(ap), "v"(packed) : "memory");
                        }
                        ra = 0.f; rb = 0.f; curd = mdst[r];
                    }
                    ra += ma; rb += mb;
                }
                if (curd >= 0) {
                    unsigned packed = packbf(ra, rb);
                    short* ap = zaccb + (size_t)curd * 128 + colbase * 8 + 2 * np;
                    asm volatile("global_atomic_pk_add_bf16 %0, %1, off"
                                 :: "v"(ap), "v"(packed) : "memory");
                }
            }
        } else if (EPI == 4) {
            float* outf = (float*)out;
            #pragma unroll
            for (int r = 0; r < 4; r++) {
                int row = rbase + r;
                if (row < M) {
                    const float4* xr = (const float4*)(xres + (size_t)row * 128 + colbase * 8);
                    float4 x0 = xr[0], x1 = xr[1];
                    float4 o0, o1;
                    o0.x = acc[0][r] + bcol[0] + x0.x;
                    o0.y = acc[1][r] + bcol[1] + x0.y;
                    o0.z = acc[2][r] + bcol[2] + x0.z;
                    o0.w = acc[3][r] + bcol[3] + x0.w;
                    o1.x = acc[4][r] + bcol[4] + x1.x;
                    o1.y = acc[5][r] + bcol[5] + x1.y;
                    o1.z = acc[6][r] + bcol[6] + x1.z;
                    o1.w = acc[7][r] + bcol[7] + x1.w;
                    float4* op = (float4*)(outf + (size_t)row * 128 + colbase * 8);
                    op[0] = o0; op[1] = o1;
                }
            }
        }
    }

    if (EPI == 2) {
        __syncthreads();
        #pragma unroll
        for (int n = 0; n < 8; n++) {
            atomicAdd(&lS[colbase * 8 + n], sreg[n]);
            atomicAdd(&lQ[colbase * 8 + n], qreg[n]);
        }
        __syncthreads();
        if (tid < 128) {
            int rep = blockIdx.x & 15;
            atomicAdd(&stats[rep * 256 + tid], lS[tid]);
            atomicAdd(&stats[rep * 256 + 128 + tid], lQ[tid]);
        }
    }
}

extern "C" void kernel_launch(void* const* d_in, const int* in_sizes, int n_in,
                              void* d_out, int out_size, void* d_ws, size_t ws_size,
                              hipStream_t stream)
{
    const float* x    = (const float*)d_in[0];
    const float* ea   = (const float*)d_in[1];
    const int*   eidx = (const int*)d_in[2];
    const float* Wb   = (const float*)d_in[3];
    const float* bb   = (const float*)d_in[4];
    const float* We1  = (const float*)d_in[5];
    const float* be1  = (const float*)d_in[6];
    const float* ge1  = (const float*)d_in[7];
    const float* bte1 = (const float*)d_in[8];
    const float* We2  = (const float*)d_in[9];
    const float* be2  = (const float*)d_in[10];
    const float* ge2  = (const float*)d_in[11];
    const float* bte2 = (const float*)d_in[12];
    const float* We3  = (const float*)d_in[13];
    const float* be3  = (const float*)d_in[14];
    const float* Wd   = (const float*)d_in[15];
    const float* bd   = (const float*)d_in[16];
    const float* vv   = (const float*)d_in[17];
    const float* Wn1  = (const float*)d_in[18];
    const float* bn1  = (const float*)d_in[19];
    const float* gn   = (const float*)d_in[20];
    const float* btn  = (const float*)d_in[21];
    const float* Wn2  = (const float*)d_in[22];
    const float* bn2  = (const float*)d_in[23];

    const int NN = in_sizes[0] / 128;   // 50000
    const int EE = in_sizes[1] / 4;     // 300000

    char* ws = (char*)d_ws;
    size_t oEZ   = 0;
    size_t oXD   = oEZ   + (size_t)EE * 256;
    size_t oXS   = oXD   + (size_t)NN * 256;
    size_t oXT   = oXS   + (size_t)NN * 256;
    size_t oZACC = oXT   + (size_t)NN * 256;
    size_t oZN   = oZACC + (size_t)NN * 256;
    size_t oTAB  = oZN   + (size_t)NN * 256;
    size_t oW1P  = oTAB  + (size_t)4 * 1025 * 256;
    size_t oB1P  = oW1P  + (size_t)200 * 512;
    size_t oBP   = oB1P  + 512;
    size_t oBIAS = oBP   + (size_t)7 * 32768;
    size_t oST   = oBIAS + (size_t)7 * 512;
    size_t oCNT  = oST   + 49152;
    size_t oPOS  = oCNT  + 201728;
    size_t oBSUM = oPOS  + 201728;
    size_t oPOS2 = oBSUM + 1024;
    size_t oSSRC = oPOS2 + 201728;
    size_t oSDST = oSSRC + (size_t)EE * 4;
    size_t oSCF  = oSDST + (size_t)EE * 4;
    size_t oSEA  = (oSCF + (size_t)EE * 4 + 15) & ~(size_t)15;

    short* eZ    = (short*)(ws + oEZ);
    short* xd    = (short*)(ws + oXD);
    short* xs1b  = (short*)(ws + oXS);
    short* xt1b  = (short*)(ws + oXT);
    short* zaccb = (short*)(ws + oZACC);
    short* zn    = (short*)(ws + oZN);
    short* tab   = (short*)(ws + oTAB);
    float* W1p   = (float*)(ws + oW1P);
    float* b1p   = (float*)(ws + oB1P);
    short* bp    = (short*)(ws + oBP);
    short* BpW2  = bp + 3 * 16384;
    short* BpW3  = bp + 4 * 16384;
    short* BpN1  = bp + 5 * 16384;
    short* BpN2  = bp + 6 * 16384;
    float* bo    = (float*)(ws + oBIAS);
    float* b2p   = bo + 0 * 128;
    float* b3p   = bo + 1 * 128;
    float* b2np  = bo + 2 * 128;
    float* st1   = (float*)(ws + oST);
    float* st2   = st1 + 4096;
    float* stN   = st1 + 8192;
    int*   cnt   = (int*)(ws + oCNT);
    int*   posE  = (int*)(ws + oPOS);
    int*   bsum  = (int*)(ws + oBSUM);
    int*   pos2  = (int*)(ws + oPOS2);
    int*   sSrc  = (int*)(ws + oSSRC);
    int*   sDst  = (int*)(ws + oSDST);
    float* scf   = (float*)(ws + oSCF);
    float4* sEa  = (float4*)(ws + oSEA);

    hipMemsetAsync(ws + oST, 0, 49152 + 201728, stream);

    build_w1p_k<<<201, 128, 0, stream>>>(Wb, We1, bb, be1, W1p, b1p);
    build_tab_k<<<dim3(1025, 4), 128, 0, stream>>>(W1p, b1p, tab);
    fold_plain_k<<<dim3(8, 4), 256, 0, stream>>>(
        Wd, We1, We1 + 256 * 128, Wn1, bp, bp + 16384, bp + 2 * 16384, BpN1);

    int nchN = (NN + 63) / 64;
    int nchE = (EE + 63) / 64;
    int gN4 = (nchN + 3) / 4;
    int gE4 = (nchE + 3) / 4;
    int nbN = (NN + 255) / 256;
    int nbE = (EE + 255) / 256;

    // fused node precompute: xd/zacc, xs1, xt1  (reads x once)
    node_all_k<<<nchN, 256, 0, stream>>>(x, NN, bp, bd, vv, xd, zaccb, xs1b, xt1b);

    // counting sort by dst
    hist_k<<<nbE, 256, 0, stream>>>(eidx + EE, cnt, EE);
    scan1_k<<<nbN, 256, 0, stream>>>(cnt, NN, posE, bsum);
    scan2_k<<<1, 256, 0, stream>>>(bsum, nbN);
    fix_k<<<nbN, 256, 0, stream>>>(posE, bsum, pos2, NN);
    scat_k<<<nbE, 256, 0, stream>>>(eidx, eidx + EE, (const float4*)ea, pos2,
                                    sSrc, sDst, scf, sEa, EE);

    edge_z1_k<<<nbE, 256, 0, stream>>>(xs1b, xt1b, tab, sSrc, sDst, sEa, eZ, st1, EE);

    fold_k<<<8, 256, 0, stream>>>(We2, be2, st1, ge1, bte1, 1.f / (float)EE, BpW2, b2p);
    pgemm_k<2><<<gE4, 256, 0, stream>>>(eZ, EE, BpW2, b2p, eZ, st2,
        nullptr, nullptr, nullptr, nullptr, nullptr, nullptr);

    fold_k<<<8, 256, 0, stream>>>(We3, be3, st2, ge2, bte2, 1.f / (float)EE, BpW3, b3p);
    pgemm_k<3><<<gE4, 256, 0, stream>>>(eZ, EE, BpW3, b3p, nullptr, nullptr,
        xd, zaccb, scf, sSrc, sDst, nullptr);

    pgemm_k<2><<<gN4, 256, 0, stream>>>(zaccb, NN, BpN1, bn1, zn, stN,
        nullptr, nullptr, nullptr, nullptr, nullptr, nullptr);

    fold_k<<<8, 256, 0, stream>>>(Wn2, bn2, stN, gn, btn, 1.f / (float)NN, BpN2, b2np);
    pgemm_k<4><<<gN4, 256, 0, stream>>>(zn, NN, BpN2, b2np, d_out, nullptr,
        nullptr, nullptr, nullptr, nullptr, nullptr, x);
}